// Round 8
// baseline (109.552 us; speedup 1.0000x reference)
//
#include <hip/hip_runtime.h>

// SoftHistogram: x[B=64, N=1000, F=256] fp32 -> out[B, F*K=2048] fp32
// out[b, f*8+k] = mean_n relu(1 - 16*|x[b,n,f] - (k+0.5)/8|)
//
// R8: single fused dispatch. R6 measured the streaming pass at 10.8 us
// (96% of read BW); the remaining ~8 us was fixed structure cost (2nd
// dispatch + gap + 4MB ws round-trip). Fuse via EXACT u32 fixed-point
// atomics (order-independent => deterministic): block partial s -> 
// round(s*2^21); Sigma <= 1000*2^21 = 2.1e9 < 2^32. Last-arriving block
// per b (rocPRIM pattern: threadfence + counter) converts to float.
// ws zeroed by hipMemsetAsync (graph-legal, harness uses it itself).

constexpr int N = 1000, F = 256, K = 8;
constexpr int CH = 8;              // n-chunks per batch row
constexpr int RC = N / CH;         // 125 rows per chunk
constexpr int WPB = 8;             // waves per block
constexpr float QSCALE = 2097152.0f;              // 2^21
constexpr float OSCALE = 4.76837158203125e-10f;   // 2^-21 / 1000

__global__ __launch_bounds__(512) void softhist_fused(const float* __restrict__ x,
                                                      unsigned* __restrict__ acc,
                                                      float* __restrict__ out) {
    __shared__ float hist[WPB * K * F];   // 8 waves x [k][slot] = 64 KB
    __shared__ int is_last;

    unsigned* cnt = acc + 64 * 2048;      // 64 counters after the accumulators

    const int bid = blockIdx.x;
    const int b  = bid >> 3;
    const int ch = bid & 7;
    const int t  = threadIdx.x;
    const int w  = t >> 6;             // wave 0..7
    const int l  = t & 63;             // lane

    // zero the histograms
#pragma unroll
    for (int z = 0; z < 8; ++z)
        *reinterpret_cast<float4*>(&hist[(z * 512 + t) * 4]) = float4{0.f, 0.f, 0.f, 0.f};
    __syncthreads();

    float* wh = &hist[w * (K * F)];
    const float* base = x + ((size_t)b * N + (size_t)ch * RC) * F + l * 4;

    auto proc = [&](const float4 v) {
        const float xs[4] = {v.x, v.y, v.z, v.w};
#pragma unroll
        for (int i = 0; i < 4; ++i) {
            const float h  = fmaf(xs[i], 8.0f, -0.5f);           // u = 8x - 0.5
            const float kf = __builtin_rintf(h);                  // v_rndne
            const float kc = __builtin_amdgcn_fmed3f(kf, 0.0f, 7.0f);
            const float y  = fmaf(-2.0f, fabsf(h - kc), 1.0f);    // 1 - 2|u-k*|
            if (y > 0.0f) {                                       // ~34% of lanes
                const int ki = (int)kc;
                wh[ki * F + (i << 6) + l] += y;   // bank = l%32: conflict-free
            }
        }
    };

    int n = w;
    for (; n + WPB < RC; n += 2 * WPB) {
        const float4 v0 = *reinterpret_cast<const float4*>(base + (size_t)n * F);
        const float4 v1 = *reinterpret_cast<const float4*>(base + (size_t)(n + WPB) * F);
        proc(v0);
        proc(v1);
    }
    if (n < RC)
        proc(*reinterpret_cast<const float4*>(base + (size_t)n * F));
    __syncthreads();

    // Reduce 8 wave-hists -> 2048 block partials (c = f*8+k), quantize,
    // atomic-accumulate into acc[b][c]. slot = k*256 + perm(f).
    const int f  = t & 255;
    const int kb = (t >> 8) * 4;
    const int pf = ((f & 3) << 6) + (f >> 2);   // perm(f)
    unsigned* ab = acc + ((size_t)b << 11);
#pragma unroll
    for (int j = 0; j < 4; ++j) {
        const int off = (kb + j) * F + pf;
        float s = 0.0f;
#pragma unroll
        for (int ww = 0; ww < WPB; ++ww) s += hist[ww * (K * F) + off];
        atomicAdd(&ab[f * 8 + kb + j], (unsigned)__float2uint_rn(s * QSCALE));
    }

    // Last-block-per-b finishes: canonical threadfence + counter pattern.
    __threadfence();
    __syncthreads();
    if (t == 0) {
        const unsigned old = atomicAdd(&cnt[b], 1u);
        is_last = (old == CH - 1);
    }
    __syncthreads();

    if (is_last) {
        __threadfence();
#pragma unroll
        for (int m = 0; m < 4; ++m) {
            const int c = t + 512 * m;                 // 0..2047
            const unsigned v = atomicAdd(&ab[c], 0u);  // coherent read
            out[((size_t)b << 11) + c] = (float)v * OSCALE;
        }
    }
}

// ---- fallback if ws is unexpectedly small ----
__global__ __launch_bounds__(1024) void softhist_mono(const float* __restrict__ x,
                                                      float* __restrict__ out) {
    constexpr int FG = 32, NSTR = 128;
    __shared__ float part[64 * 264];
    const int bid = blockIdx.x;
    const int b = bid >> 3, f0 = (bid & 7) * FG;
    const int t = threadIdx.x;
    const int fl8 = t & 7, nsub = t >> 3;
    const int w = t >> 6, l = t & 63;

    float acc[4][K];
#pragma unroll
    for (int i = 0; i < 4; ++i)
#pragma unroll
        for (int k = 0; k < K; ++k) acc[i][k] = 0.0f;

    const float* base = x + (size_t)b * N * F + f0 + fl8 * 4;
#define PROC4(v)                                                             \
    {                                                                        \
        const float xs[4] = {(v).x, (v).y, (v).z, (v).w};                    \
        _Pragma("unroll")                                                    \
        for (int i = 0; i < 4; ++i) {                                        \
            const float p = fmaf(xs[i], 16.0f, -1.0f);                       \
            float aprev = -1.0f - p;                                         \
            _Pragma("unroll")                                                \
            for (int k = 0; k < K; ++k) {                                    \
                const float a = (float)(2 * k + 1) - p;                      \
                acc[i][k] += __builtin_amdgcn_fmed3f(0.0f, a, -aprev);       \
                aprev = a;                                                   \
            }                                                                \
        }                                                                    \
    }
    int n = nsub;
    for (; n + NSTR < N; n += 2 * NSTR) {
        const float4 v0 = *reinterpret_cast<const float4*>(base + (size_t)n * F);
        const float4 v1 = *reinterpret_cast<const float4*>(base + (size_t)(n + NSTR) * F);
        PROC4(v0);
        PROC4(v1);
    }
    if (n < N) {
        const float4 v = *reinterpret_cast<const float4*>(base + (size_t)n * F);
        PROC4(v);
    }
#undef PROC4
#pragma unroll
    for (int i = 0; i < 4; ++i)
#pragma unroll
        for (int k = 0; k < K; ++k) acc[i][k] += __shfl_xor(acc[i][k], 32, 64);
    if (l < 32) {
        const int g = w * 4 + (l >> 3);
        float* dst = &part[g * 264 + fl8 * 33];
#pragma unroll
        for (int i = 0; i < 4; ++i)
#pragma unroll
            for (int k = 0; k < K; ++k) dst[i * 8 + k] = acc[i][k];
    }
    __syncthreads();
    if (t < FG * K) {
        const int off = (t >> 5) * 33 + (t & 31);
        float s = 0.0f;
#pragma unroll
        for (int g = 0; g < 64; ++g) s += part[g * 264 + off];
        out[(size_t)b * (F * K) + f0 * K + t] = s * (1.0f / (float)N);
    }
}

extern "C" void kernel_launch(void* const* d_in, const int* in_sizes, int n_in,
                              void* d_out, int out_size, void* d_ws, size_t ws_size,
                              hipStream_t stream) {
    const float* x = (const float*)d_in[0];
    float* out = (float*)d_out;
    const size_t ws_needed = ((size_t)64 * 2048 + 64) * sizeof(unsigned);  // 516 KB
    if (ws_size >= ws_needed) {
        unsigned* acc = (unsigned*)d_ws;
        hipMemsetAsync(acc, 0, ws_needed, stream);
        softhist_fused<<<dim3(512), dim3(512), 0, stream>>>(x, acc, out);
    } else {
        softhist_mono<<<dim3(512), dim3(1024), 0, stream>>>(x, out);
    }
}

// Round 9
// 17.422 us; speedup vs baseline: 6.2882x; 6.2882x over previous
//
#include <hip/hip_runtime.h>

// SoftHistogram: x[B=64, N=1000, F=256] fp32 -> out[B, F*K=2048] fp32
// out[b, f*8+k] = mean_n relu(1 - 16*|x[b,n,f] - (k+0.5)/8|)
//
// R9: single dispatch, zero cross-block communication (R8's atomic/fence
// fusion was a 5x regression: 1M uncoalesced device-scope atomics).
// Block = (b, 32-feature slice) [R2's proven strided layout: wave-load =
// 8 rows x 128 B]. Inner loop = nearest-bin (R5): u = 8x-0.5,
// k* = clamp(round(u),0,7), y = relu(1-2|u-k*|) -- at most one nonzero bin.
// Wave-private LDS hist, lane-unique slot ki*256 + i*64 + l (bank = l%32,
// conflict-free; R7's fix). Cold reduce: g-staggered gather -> 32 banks.
// 512 blocks x 512 thr, 64 KB LDS -> 2 blocks/CU, 16 waves/CU. No ws.

constexpr int N = 1000, F = 256, K = 8;
constexpr int FG = 32;             // features per block
constexpr int WPB = 8;             // waves per block
constexpr int NS = 64;             // n-subgroups (t>>3)

__global__ __launch_bounds__(512) void softhist_mono(const float* __restrict__ x,
                                                     float* __restrict__ out) {
    __shared__ float hist[WPB * K * F];   // 8 waves x [k][256 slots] = 64 KB

    const int bid = blockIdx.x;
    const int b  = bid >> 3;
    const int f0 = (bid & 7) * FG;
    const int t  = threadIdx.x;
    const int w  = t >> 6;             // wave 0..7
    const int l  = t & 63;             // lane
    // lane l covers features f_local = (l&7)*4 + i, n-subgroup nsub = t>>3

    // zero the histograms (16K floats, 8 float4 stores/thread)
#pragma unroll
    for (int z = 0; z < 8; ++z)
        *reinterpret_cast<float4*>(&hist[(z * 512 + t) * 4]) = float4{0.f, 0.f, 0.f, 0.f};
    __syncthreads();

    float* wh = &hist[w * (K * F)];
    const int nsub = t >> 3;
    const float* base = x + (size_t)b * N * F + f0 + (l & 7) * 4;

    auto proc = [&](const float4 v) {
        const float xs[4] = {v.x, v.y, v.z, v.w};
#pragma unroll
        for (int i = 0; i < 4; ++i) {
            const float h  = fmaf(xs[i], 8.0f, -0.5f);           // u = 8x - 0.5
            const float kf = __builtin_rintf(h);                  // v_rndne
            const float kc = __builtin_amdgcn_fmed3f(kf, 0.0f, 7.0f);
            const float y  = fmaf(-2.0f, fabsf(h - kc), 1.0f);    // 1 - 2|u-k*|
            if (y > 0.0f) {                                       // ~34% of lanes
                const int ki = (int)kc;
                wh[ki * F + (i << 6) + l] += y;   // bank = l%32: conflict-free
            }
        }
    };

    int n = nsub;
    for (; n + NS < N; n += 2 * NS) {
        const float4 v0 = *reinterpret_cast<const float4*>(base + (size_t)n * F);
        const float4 v1 = *reinterpret_cast<const float4*>(base + (size_t)(n + NS) * F);
        proc(v0);
        proc(v1);
    }
    if (n < N)
        proc(*reinterpret_cast<const float4*>(base + (size_t)n * F));
    __syncthreads();

    // Reduce: output (f in [0,32), k in [0,8)) = sum over wave w, group g of
    // slot[w][k*256 + (f&3)*64 + g*8 + (f>>2)]   (l = g*8 + (f&7-bits))
    // g staggered per lane: g' = (g + (f&7)) & 7 -> banks = ((g+f%8)%8)*8 +
    // f>>2 : 32 distinct banks across f (2 k-lanes each = free).
    if (t < FG * K) {   // 256 threads
        const int f = t & 31;
        const int k = t >> 5;
        const int slot_base = k * F + ((f & 3) << 6) + (f >> 2);
        float s = 0.0f;
#pragma unroll
        for (int w2 = 0; w2 < WPB; ++w2)
#pragma unroll
            for (int g = 0; g < 8; ++g) {
                const int gp = (g + (f & 7)) & 7;
                s += hist[w2 * (K * F) + slot_base + gp * 8];
            }
        out[(size_t)b * (F * K) + (f0 + f) * K + k] = s * (1.0f / (float)N);
    }
}

extern "C" void kernel_launch(void* const* d_in, const int* in_sizes, int n_in,
                              void* d_out, int out_size, void* d_ws, size_t ws_size,
                              hipStream_t stream) {
    const float* x = (const float*)d_in[0];
    float* out = (float*)d_out;
    // 64 b x 8 f-slices -> 512 blocks of 512 threads (2 blocks/CU)
    softhist_mono<<<dim3(512), dim3(512), 0, stream>>>(x, out);
}